// Round 12
// baseline (71.450 us; speedup 1.0000x reference)
//
#include <hip/hip_runtime.h>

typedef __attribute__((ext_vector_type(8))) _Float16 half8;
typedef __attribute__((ext_vector_type(4))) _Float16 half4v;
typedef __attribute__((ext_vector_type(4))) float f32x4;
typedef float f32x4u __attribute__((ext_vector_type(4), aligned(4)));

#define EPSF 1e-6f

__device__ __forceinline__ void glds16(const void* g, void* l) {
    __builtin_amdgcn_global_load_lds(
        (const __attribute__((address_space(1))) unsigned*)g,
        (__attribute__((address_space(3))) unsigned*)l, 16, 0, 0);
}

// ---------------------------------------------------------------------------
// prep: Mh[f][768] = fp16 of stacked [A|Bw|Cw] (K-contig); Wh[g][256] = fp16(W).
// ---------------------------------------------------------------------------
__global__ __launch_bounds__(256) void prep_kernel(
    const float* __restrict__ A, const float* __restrict__ Bw,
    const float* __restrict__ Cw, const float* __restrict__ W,
    _Float16* __restrict__ Mh, _Float16* __restrict__ Wh)
{
    int f = blockIdx.x, e = threadIdx.x;
    Mh[f * 768 + e]       = (_Float16)A[f * 256 + e];
    Mh[f * 768 + 256 + e] = (_Float16)Bw[f * 256 + e];
    Mh[f * 768 + 512 + e] = (_Float16)Cw[f * 256 + e];
    Wh[f * 256 + e]       = (_Float16)W[f * 256 + e];
}

// ---------------------------------------------------------------------------
// fused v8: LANE-LOCAL T.  B-frag layout (lane: col=lr, k=lq*8..+8) + c-map
// c = i*64 + wc*16 + lr  =>  each lane's 9 bf values per eb are the 9 terms
// (3t x 3i) of ONE point-set (n = wc*16+lr, e = eb*32+lq*8..+8), computed
// in-register.  T never touches LDS: no T writes, no bf reads, no T barriers.
// Waves: 4 wc (16n each, 64n block) x 2 wf (128f each).  acc[3i][8mi].
// A (M) staged per eb (3 t-slices, 48 KB) double-buffered via glds16; ONE
// barrier per eb.  part2: Y->LDS (192 x 512B swz), GEMM2 + VN epilogue.
// LDS: max(2x49152 part1, 98304 part2 Y) = 98304 -> 1 block/CU, 8 waves.
// grid 256 (b x 16 n-tiles of 64); 512 thr; __launch_bounds__(512,2).
// ---------------------------------------------------------------------------
__global__ __launch_bounds__(512, 2) void fused_kernel(
    const float* __restrict__ X, const float* __restrict__ Jp,
    const _Float16* __restrict__ Mh, const _Float16* __restrict__ Wh,
    float* __restrict__ out)
{
    extern __shared__ char lds[];
    int tid = threadIdx.x;
    int b  = blockIdx.x >> 4;
    int n0 = (blockIdx.x & 15) * 64;

    int l = tid & 63, lr = l & 15, lq = l >> 4;
    int w = tid >> 6, wf = w & 1, wc = w >> 1;     // wf: f-half, wc: n-group

    // stage 3 t-slices of M[., eb*32..+32] (48 KB) into A[p]
    auto stageEB = [&](int p, int eb) {
        #pragma unroll
        for (int h = 0; h < 6; ++h) {
            int m = h * 512 + tid;                  // 0..3071
            int t = m >> 10, fr = (m >> 2) & 255, slot = m & 3;
            size_t go = ((size_t)fr * 768 + t * 256 + eb * 32
                         + ((slot ^ ((fr >> 1) & 3)) * 8)) * 2;
            glds16((const char*)Mh + go, lds + p * 49152 + m * 16);
        }
    };

    f32x4 acc[3][8] = {};

    // per-lane X/J base: point set (n = n0 + wc*16 + lr, e = eb*32 + lq*8 + j)
    size_t pb0 = ((size_t)((b * 1024 + n0 + wc * 16 + lr) * 256) + lq * 8) * 3;

    stageEB(0, 0);
    __syncthreads();

    for (int eb = 0; eb < 8; ++eb) {
        int cur = eb & 1;
        if (eb < 7) stageEB(cur ^ 1, eb + 1);       // async; drains at eb-end barrier

        // ---- load X/J (24 floats each, contiguous) ----
        size_t pb = pb0 + (size_t)eb * 96;
        float xa[24], ja[24];
        #pragma unroll
        for (int h = 0; h < 6; ++h) {
            f32x4u xv = *(const f32x4u*)(X + pb + h * 4);
            f32x4u jv = *(const f32x4u*)(Jp + pb + h * 4);
            xa[h*4+0] = xv[0]; xa[h*4+1] = xv[1]; xa[h*4+2] = xv[2]; xa[h*4+3] = xv[3];
            ja[h*4+0] = jv[0]; ja[h*4+1] = jv[1]; ja[h*4+2] = jv[2]; ja[h*4+3] = jv[3];
        }

        // ---- basis + terms for 8 points -> bf[t][i] half8 (registers only) ----
        half8 bf[3][3];
        #pragma unroll
        for (int j = 0; j < 8; ++j) {
            float x0 = xa[3*j], x1 = xa[3*j+1], x2 = xa[3*j+2];
            float j0 = ja[3*j], j1 = ja[3*j+1], j2 = ja[3*j+2];
            float jj  = j0*j0 + j1*j1 + j2*j2;
            float rn  = __builtin_amdgcn_rcpf(__builtin_amdgcn_sqrtf(jj) + EPSF);
            float nj0 = j0*rn, nj1 = j1*rn, nj2 = j2*rn;
            float s2  = nj0*nj0 + nj1*nj1;
            float uz  = -s2 * __builtin_amdgcn_rcpf(nj2 + EPSF);
            float ru  = __builtin_amdgcn_rcpf(__builtin_amdgcn_sqrtf(s2 + uz*uz) + EPSF);
            float u0 = nj0*ru, u1 = nj1*ru, u2 = uz*ru;
            float v0 = u1*nj2 - u2*nj1;
            float v1 = u2*nj0 - u0*nj2;
            float v2 = u0*nj1 - u1*nj0;
            float r0 = u0*x0 + v0*x1 + nj0*x2;
            float r1 = u1*x0 + v1*x1 + nj1*x2;
            float r2 = u2*x0 + v2*x1 + nj2*x2;
            bf[0][0][j] = (_Float16)(u0*r0 + u1*r1);
            bf[0][1][j] = (_Float16)(v0*r0 + v1*r1);
            bf[0][2][j] = (_Float16)(nj0*r0 + nj1*r1);
            bf[1][0][j] = (_Float16)(u1*r0 - u0*r1);
            bf[1][1][j] = (_Float16)(v1*r0 - v0*r1);
            bf[1][2][j] = (_Float16)(nj1*r0 - nj0*r1);
            bf[2][0][j] = (_Float16)(u2*r2);
            bf[2][1][j] = (_Float16)(v2*r2);
            bf[2][2][j] = (_Float16)(nj2*r2);
        }

        // ---- 3 t-steps: af from A[cur] (LDS), MFMA (no barriers inside) ----
        #pragma unroll
        for (int t = 0; t < 3; ++t) {
            half8 af[8];
            #pragma unroll
            for (int mi = 0; mi < 8; ++mi) {
                int f = wf * 128 + mi * 16 + lr;
                af[mi] = *(const half8*)(lds + cur * 49152 + t * 16384 + f * 64
                                         + ((lq ^ ((f >> 1) & 3)) * 16));
            }
            #pragma unroll
            for (int i = 0; i < 3; ++i)
                #pragma unroll
                for (int mi = 0; mi < 8; ++mi)
                    acc[i][mi] = __builtin_amdgcn_mfma_f32_16x16x32_f16(
                        af[mi], bf[t][i], acc[i][mi], 0, 0, 0);
        }
        __syncthreads();          // A[cur] reads done; A[nxt] staged
    }

    // ---------------- part 2: Y -> LDS, GEMM2 + VN epilogue ----------------
    // Y tile: 192 rows (c = i*64 + n_loc) x 512 B, byte ^= (c&7)<<4
    #pragma unroll
    for (int i = 0; i < 3; ++i) {
        int c = i * 64 + wc * 16 + lr;
        #pragma unroll
        for (int mi = 0; mi < 8; ++mi) {
            int fb2 = (wf * 128 + mi * 16 + lq * 4) * 2;
            f32x4 v = acc[i][mi];
            half4v p;
            p.x = (_Float16)v[0]; p.y = (_Float16)v[1];
            p.z = (_Float16)v[2]; p.w = (_Float16)v[3];
            *(half4v*)(lds + c * 512 + (fb2 ^ ((c & 7) << 4))) = p;
        }
    }

    int nh = w & 1, gw = w >> 1;   // re-tile: 2 n-halves (32) x 4 g-quarters (64)
    half8 wreg[2][4];
    #pragma unroll
    for (int gf = 0; gf < 4; ++gf) {
        int g = gw * 64 + gf * 16 + lr;
        wreg[0][gf] = *(const half8*)(Wh + (size_t)g * 256 + lq * 8);
    }
    __syncthreads();               // Y_lds visible

    f32x4 acc2[3][2][4] = {};
    #pragma unroll
    for (int kt = 0; kt < 8; ++kt) {
        if (kt < 7) {
            #pragma unroll
            for (int gf = 0; gf < 4; ++gf) {
                int g = gw * 64 + gf * 16 + lr;
                wreg[(kt + 1) & 1][gf] =
                    *(const half8*)(Wh + (size_t)g * 256 + (kt + 1) * 32 + lq * 8);
            }
        }
        #pragma unroll
        for (int ci = 0; ci < 3; ++ci)
            #pragma unroll
            for (int nc = 0; nc < 2; ++nc) {
                int c = ci * 64 + nh * 32 + nc * 16 + lr;
                half8 yf = *(const half8*)(lds + c * 512
                             + ((kt * 64 + lq * 16) ^ ((c & 7) << 4)));
                #pragma unroll
                for (int gf = 0; gf < 4; ++gf)
                    acc2[ci][nc][gf] = __builtin_amdgcn_mfma_f32_16x16x32_f16(
                        yf, wreg[kt & 1][gf], acc2[ci][nc][gf], 0, 0, 0);
            }
    }

    // epilogue: lane holds d_i for (g = gw*64+gf*16+lr, n = nh*32+nc*16+lq*4+r)
    #pragma unroll
    for (int nc = 0; nc < 2; ++nc)
        #pragma unroll
        for (int gf = 0; gf < 4; ++gf) {
            int g = gw * 64 + gf * 16 + lr;
            f32x4 o[3];
            #pragma unroll
            for (int r = 0; r < 4; ++r) {
                float xv[3];
                #pragma unroll
                for (int ci = 0; ci < 3; ++ci) {
                    int c = ci * 64 + nh * 32 + nc * 16 + lq * 4 + r;
                    xv[ci] = (float)*(const _Float16*)(lds + c * 512
                                     + ((g * 2) ^ ((c & 7) << 4)));
                }
                float d0 = acc2[0][nc][gf][r], d1 = acc2[1][nc][gf][r], d2 = acc2[2][nc][gf][r];
                float dot = xv[0] * d0 + xv[1] * d1 + xv[2] * d2;
                float dn  = d0 * d0 + d1 * d1 + d2 * d2;
                float sc  = dot / (dn + EPSF);
                bool pos  = dot >= 0.0f;
                float l0 = pos ? xv[0] : fmaf(-sc, d0, xv[0]);
                float l1 = pos ? xv[1] : fmaf(-sc, d1, xv[1]);
                float l2 = pos ? xv[2] : fmaf(-sc, d2, xv[2]);
                o[0][r] = fmaf(0.8f, l0, 0.2f * xv[0]);
                o[1][r] = fmaf(0.8f, l1, 0.2f * xv[1]);
                o[2][r] = fmaf(0.8f, l2, 0.2f * xv[2]);
            }
            int nb = n0 + nh * 32 + nc * 16 + lq * 4;
            #pragma unroll
            for (int i = 0; i < 3; ++i)
                *(f32x4*)(out + ((size_t)(b * 256 + g) * 3 + i) * 1024 + nb) = o[i];
        }
}

extern "C" void kernel_launch(void* const* d_in, const int* in_sizes, int n_in,
                              void* d_out, int out_size, void* d_ws, size_t ws_size,
                              hipStream_t stream)
{
    const float* X  = (const float*)d_in[0];
    const float* J  = (const float*)d_in[1];
    const float* A  = (const float*)d_in[2];
    const float* Bw = (const float*)d_in[3];
    const float* Cw = (const float*)d_in[4];
    const float* W  = (const float*)d_in[5];
    float* out = (float*)d_out;

    char* ws = (char*)d_ws;
    _Float16* Mh = (_Float16*)ws;                       // 256*768*2 = 393216
    _Float16* Wh = (_Float16*)(ws + 393216);            // 256*256*2 = 131072

    (void)hipFuncSetAttribute((const void*)fused_kernel,
                              hipFuncAttributeMaxDynamicSharedMemorySize, 98304);

    hipLaunchKernelGGL(prep_kernel,  dim3(256), dim3(256), 0, stream,
                       A, Bw, Cw, W, Mh, Wh);
    hipLaunchKernelGGL(fused_kernel, dim3(256), dim3(512), 98304, stream,
                       X, J, Mh, Wh, out);
}